// Round 13
// baseline (154.217 us; speedup 1.0000x reference)
//
#include <hip/hip_runtime.h>
#include <hip/hip_bf16.h>
#include <stdint.h>

#define BB   16
#define NN   1024
#define KSEL 170   // (32*32)/6
#define LOG2E 1.4426950408889634f

typedef __attribute__((ext_vector_type(8))) short short8;
typedef __attribute__((ext_vector_type(4))) short short4v;
typedef __attribute__((ext_vector_type(4))) float f32x4;
typedef __attribute__((ext_vector_type(2))) float float2v;

static __device__ __forceinline__ short f2bf(float x) {
    __hip_bfloat16 h = __float2bfloat16(x);
    return *reinterpret_cast<short*>(&h);
}
static __device__ __forceinline__ float bf2f(short x) {
    uint32_t u = ((uint32_t)(uint16_t)x) << 16;
    return __uint_as_float(u);
}
static __device__ __forceinline__ float fast_exp2(float x) {
    float r; asm("v_exp_f32 %0, %1" : "=v"(r) : "v"(x)); return r;
}

// ---------------- K1: exact k-th-largest per row (one row/wave) + fused prep ---------
// Ballot-based binary radix select: 32 bits, count via v_cmp+ballot+s_bcnt (wave-
// uniform SGPR count) -> zero LDS, zero atomics, zero shuffle chains. Exact for ties.
// blocks [0,4096): one row per wave; blocks [4096,5760): independent prep work.
__global__ __launch_bounds__(256) void k_topk_mask(
    const float* __restrict__ adj, uint64_t* __restrict__ mask,
    const float* __restrict__ W0, const float* __restrict__ rW0,
    const float* __restrict__ W1, const float* __restrict__ rW1,
    const float* __restrict__ seg,
    short* __restrict__ Wt0, short* __restrict__ rWt0,
    short* __restrict__ Wt1, short* __restrict__ rWt1,
    short* __restrict__ xb0)
{
    const int bid = blockIdx.x, t = threadIdx.x;
    if (bid >= 4096) {                                 // ---- prep roles ----
        const int pid = bid - 4096;
        if (pid < 64) {                  // Wt0 [256][64]
            int idx = pid * 256 + t;
            int o = idx >> 6, k = idx & 63;
            Wt0[idx] = f2bf(W0[(size_t)k * 256 + o]);
        } else if (pid < 128) {          // rWt0 [256][64]
            int idx = (pid - 64) * 256 + t;
            int o = idx >> 6, k = idx & 63;
            rWt0[idx] = f2bf(rW0[(size_t)k * 256 + o]);
        } else if (pid < 384) {          // Wt1 [256][256]
            int idx = (pid - 128) * 256 + t;
            int o = idx >> 8, k = idx & 255;
            Wt1[idx] = f2bf(W1[(size_t)k * 256 + o]);
        } else if (pid < 640) {          // rWt1 [256][256]
            int idx = (pid - 384) * 256 + t;
            int o = idx >> 8, k = idx & 255;
            rWt1[idx] = f2bf(rW1[(size_t)k * 256 + o]);
        } else {                         // seg fp32 -> bf16 (1M elems, 4/thread)
            int i = ((pid - 640) * 256 + t) * 4;
            float4 v = *(const float4*)(seg + i);
            short4v o4;
            o4[0] = f2bf(v.x); o4[1] = f2bf(v.y); o4[2] = f2bf(v.z); o4[3] = f2bf(v.w);
            *(short4v*)(xb0 + i) = o4;
        }
        return;
    }

    const int wid = t >> 6, lane = t & 63;
    const int row = bid * 4 + wid;                     // b*N + u
    const float* a = adj + (size_t)row * NN;

    uint32_t key[16];
    #pragma unroll
    for (int j = 0; j < 16; ++j) {
        uint32_t u = __float_as_uint(a[lane + j * 64]);
        key[j] = u ^ ((u >> 31) ? 0xFFFFFFFFu : 0x80000000u);   // order-preserving map
    }

    // ---- binary radix select: prefix accumulates the exact kk-th largest key ----
    uint32_t prefix = 0u, kk = KSEL;
    #pragma unroll
    for (int b = 31; b >= 0; --b) {
        const uint32_t bit = 1u << b;
        const uint32_t msk = ~(bit - 1u);              // bits >= b
        const uint32_t cand = prefix | bit;
        uint32_t cnt = 0;
        #pragma unroll
        for (int j = 0; j < 16; ++j)
            cnt += (uint32_t)__popcll(__ballot((key[j] & msk) == cand));
        // wave-uniform scalar update (branchless cselect)
        const bool take = (cnt >= kk);
        prefix = take ? cand : prefix;
        kk     = take ? kk   : kk - cnt;
    }
    const uint32_t thr_key = prefix;                   // key of k-th largest (exact)

    #pragma unroll
    for (int j = 0; j < 16; ++j) {
        bool pred = (key[j] >= thr_key) && (key[j] > 0x80000000u);   // adj>=thr && adj>0
        uint64_t bal = __ballot(pred);
        if (lane == 0) mask[(size_t)row * 16 + j] = bal;
    }
}

// ---------------- K1b: 64x64 bit-transpose of the mask (ballot-based) ----------------
__global__ __launch_bounds__(256) void k_maskT(
    const uint64_t* __restrict__ mask, uint64_t* __restrict__ maskT)
{
    const int tile = blockIdx.x * 4 + (threadIdx.x >> 6);  // b*256 + uw*16 + vw
    const int lane = threadIdx.x & 63;
    const int b  = tile >> 8;
    const int uw = (tile >> 4) & 15;
    const int vw = tile & 15;
    const size_t bN = (size_t)b * NN;
    uint64_t w = mask[(bN + uw * 64 + lane) * 16 + vw];
    uint64_t r_out = 0;
    #pragma unroll
    for (int j = 0; j < 64; ++j) {
        uint64_t r = __ballot((w >> j) & 1ull);
        if (lane == j) r_out = r;
    }
    maskT[(bN + vw * 64 + lane) * 16 + uw] = r_out;
}

// ---------------- K2: MFMA features — 32 nodes/block, 1 head/wave --------------------
template<int K>
__global__ __launch_bounds__(256, 2) void k_features_mfma(
    const short* __restrict__ xb,   // [B*N][K] bf16 row-major
    const short* __restrict__ Wt,   // [256][K] bf16
    const short* __restrict__ rWt,  // [256][K] bf16
    const float* __restrict__ al,   // [256]
    const float* __restrict__ ar,   // [256]
    short* __restrict__ ft,         // tiled transposed features [bh][ut16][g8][d64][ui8]
    short* __restrict__ fea,        // [B*N][256] bf16: res written here (may alias xb)
    float* __restrict__ el_t,       // [(b*4+h)][NN] scaled by LOG2E
    float* __restrict__ er_t)       // [(b*4+h)][NN] scaled by LOG2E
{
    const int tid = threadIdx.x, lane = tid & 63, hh = tid >> 6;
    const int l15 = lane & 15, l4 = lane >> 4;
    const int n0 = blockIdx.x * 32;              // block's 32-node strip
    const int b_idx = n0 >> 10;                  // NN = 1024
    const int nloc = n0 & (NN - 1);
    const int bh = b_idx * 4 + hh;
    const int XP = K + 8;                        // padded LDS row stride (shorts)

    __shared__ short x_lds[32 * (K + 8)];

    const int CH = K / 8;                        // short8 chunks per row
    #pragma unroll
    for (int c = tid; c < 32 * CH; c += 256) {
        const int row = c / CH, col = c - row * CH;
        *(short8*)&x_lds[row * XP + col * 8] =
            *(const short8*)(xb + ((size_t)n0 + row) * K + col * 8);
    }
    __syncthreads();

    const short* wbase = Wt  + (size_t)(hh * 64 + l15) * K + l4 * 8;
    const short* rbase = rWt + (size_t)(hh * 64 + l15) * K + l4 * 8;
    const size_t qs = (size_t)16 * K;

    f32x4 accf[2][4], accr[2][4];
    #pragma unroll
    for (int s = 0; s < 2; ++s)
        #pragma unroll
        for (int q = 0; q < 4; ++q) {
            accf[s][q] = (f32x4){0.f, 0.f, 0.f, 0.f};
            accr[s][q] = (f32x4){0.f, 0.f, 0.f, 0.f};
        }

    short8 bufW[2][4], bufR[2][4];
    #pragma unroll
    for (int q = 0; q < 4; ++q) {
        bufW[0][q] = *(const short8*)(wbase + q * qs);
        bufR[0][q] = *(const short8*)(rbase + q * qs);
    }

    #pragma unroll
    for (int ks = 0; ks < K / 32; ++ks) {
        const int cur = ks & 1, nxt = cur ^ 1;
        if (ks + 1 < K / 32) {                   // prefetch next ks weight fragments
            #pragma unroll
            for (int q = 0; q < 4; ++q) {
                bufW[nxt][q] = *(const short8*)(wbase + q * qs + (ks + 1) * 32);
                bufR[nxt][q] = *(const short8*)(rbase + q * qs + (ks + 1) * 32);
            }
            __builtin_amdgcn_sched_barrier(0);   // pin load-issue before MFMA block
        }
        short8 x0 = *(const short8*)&x_lds[l15 * XP + ks * 32 + l4 * 8];
        short8 x1 = *(const short8*)&x_lds[(16 + l15) * XP + ks * 32 + l4 * 8];
        #pragma unroll
        for (int q = 0; q < 4; ++q) {
            accf[0][q] = __builtin_amdgcn_mfma_f32_16x16x32_bf16(x0, bufW[cur][q], accf[0][q], 0, 0, 0);
            accf[1][q] = __builtin_amdgcn_mfma_f32_16x16x32_bf16(x1, bufW[cur][q], accf[1][q], 0, 0, 0);
            accr[0][q] = __builtin_amdgcn_mfma_f32_16x16x32_bf16(bufR[cur][q], x0, accr[0][q], 0, 0, 0);
            accr[1][q] = __builtin_amdgcn_mfma_f32_16x16x32_bf16(bufR[cur][q], x1, accr[1][q], 0, 0, 0);
        }
    }

    #pragma unroll
    for (int s = 0; s < 2; ++s) {
        const int nl = nloc + s * 16;
        #pragma unroll
        for (int q = 0; q < 4; ++q) {
            short4v pk;
            #pragma unroll
            for (int r = 0; r < 4; ++r) pk[r] = f2bf(accf[s][q][r]);
            const int dl = q * 16 + l15;         // head-local d
            const size_t idx = ((size_t)bh << 16)
                             + (size_t)(nl >> 6) * 4096
                             + (size_t)(((nl & 63) >> 3) + (l4 >> 1)) * 512
                             + (size_t)dl * 8 + (l4 & 1) * 4;
            *(short4v*)(ft + idx) = pk;
        }
        float elv[4] = {0.f, 0.f, 0.f, 0.f}, erv[4] = {0.f, 0.f, 0.f, 0.f};
        #pragma unroll
        for (int q = 0; q < 4; ++q) {
            const float alv = al[hh * 64 + q * 16 + l15];
            const float arv = ar[hh * 64 + q * 16 + l15];
            #pragma unroll
            for (int r = 0; r < 4; ++r) {
                elv[r] = fmaf(accf[s][q][r], alv, elv[r]);
                erv[r] = fmaf(accf[s][q][r], arv, erv[r]);
            }
        }
        #pragma unroll
        for (int r = 0; r < 4; ++r) {
            #pragma unroll
            for (int off = 1; off < 16; off <<= 1) {
                elv[r] += __shfl_xor(elv[r], off);
                erv[r] += __shfl_xor(erv[r], off);
            }
        }
        if (l15 == 0) {                          // 4 lanes (l4=0..3), rows nl+l4*4+r
            float4 e4, r4;
            e4.x = elv[0] * LOG2E; e4.y = elv[1] * LOG2E;
            e4.z = elv[2] * LOG2E; e4.w = elv[3] * LOG2E;
            r4.x = erv[0] * LOG2E; r4.y = erv[1] * LOG2E;
            r4.z = erv[2] * LOG2E; r4.w = erv[3] * LOG2E;
            *(float4*)(el_t + (size_t)bh * NN + nl + l4 * 4) = e4;
            *(float4*)(er_t + (size_t)bh * NN + nl + l4 * 4) = r4;
        }
        #pragma unroll
        for (int q = 0; q < 4; ++q) {
            short4v pk;
            #pragma unroll
            for (int r = 0; r < 4; ++r) pk[r] = f2bf(accr[s][q][r]);
            *(short4v*)(fea + ((size_t)n0 + s * 16 + l15) * 256 + hh * 64 + q * 16 + l4 * 4) = pk;
        }
    }
}

// ---------------- K4: masked softmax + MFMA PV + residual + bias (+ELU) --------------
// 4 waves x 16 v; f-tile TRIPLE-buffered in LDS, 2-deep prefetch.
template<int ELU_ON>
__global__ __launch_bounds__(256, 4) void k_attn(
    const short* __restrict__ ft,     // tiled [bh][ut16][g8][d64][ui8]
    const float* __restrict__ el_t,   // [(b*4+h)][NN] scaled
    const float* __restrict__ er_t,   // [(b*4+h)][NN] scaled
    const uint64_t* __restrict__ maskT,// [b*N + v][16] u-words
    const float* __restrict__ bias,   // [256]
    short* fea)                       // [B*N][256] bf16: res in, out in-place
{
    // XCD swizzle: 1024 blocks, 128 per XCD (8 full bh strips per XCD)
    const int id = blockIdx.x;
    const int swz = (id & 7) * 128 + (id >> 3);
    const int b  = swz >> 6;
    const int h  = (swz >> 4) & 3;
    const int vt = swz & 15;
    const int tid = threadIdx.x;
    const int lane = tid & 63, wid = tid >> 6;
    const int l15 = lane & 15, l4 = lane >> 4;
    const int bh = b * 4 + h;
    const size_t bN = (size_t)b * NN;
    const int v0 = vt * 64;

    __shared__ __align__(16) short f_lds[3][4096];      // [buf][g*512 + d*8 + ui]
    __shared__ __align__(16) float el_lds[NN];
    __shared__ __align__(16) uint64_t m_lds[64 * 17];   // 136B row stride
    __shared__ float smax[4];

    const short* gsrc = ft + ((size_t)bh << 16);

    // ---- prologue staging: tile 0 -> buf0, el strip (+ block max), mask rows ----
    {
        short8 sa = *(const short8*)(gsrc + tid * 8);
        short8 sb = *(const short8*)(gsrc + 2048 + tid * 8);
        float4 ev4 = ((const float4*)(el_t + (size_t)bh * NN))[tid];
        ((float4*)el_lds)[tid] = ev4;
        float m = fmaxf(fmaxf(ev4.x, ev4.y), fmaxf(ev4.z, ev4.w));
        #pragma unroll
        for (int off = 32; off; off >>= 1) m = fmaxf(m, __shfl_xor(m, off));
        if (lane == 0) smax[wid] = m;
        #pragma unroll
        for (int i = 0; i < 4; ++i) {
            int idx = tid + i * 256;           // 1024 uint64 words
            m_lds[(idx >> 4) * 17 + (idx & 15)] =
                maskT[(bN + v0 + (idx >> 4)) * 16 + (idx & 15)];
        }
        *(short8*)&f_lds[0][tid * 8] = sa;
        *(short8*)&f_lds[0][2048 + tid * 8] = sb;
    }

    // prefetch tile 1 into register set A (lands during barrier + constants)
    short8 Aa = *(const short8*)(gsrc + 4096 + tid * 8);
    short8 Ab = *(const short8*)(gsrc + 4096 + 2048 + tid * 8);

    const int vlo = wid * 16 + l15;
    const float er_lo = er_t[(size_t)bh * NN + v0 + vlo];

    __syncthreads();

    const float emx = fmaxf(fmaxf(smax[0], smax[1]), fmaxf(smax[2], smax[3]));
    const float e0 = emx + er_lo;
    const float cv_lo = fmaxf(e0, 0.2f * e0);    // lrelu monotone -> valid shift
    const float c1_lo = er_lo - cv_lo, c2_lo = 0.2f * er_lo - cv_lo;
    const float2v c1s = {c1_lo, c1_lo};
    const float2v c2s = {c2_lo, c2_lo};
    const float2v k02 = {0.2f, 0.2f};

    const uint8_t* mbytes = (const uint8_t*)m_lds;
    const int moff_lo = vlo * 136;

    short8 ones8;
    #pragma unroll
    for (int i = 0; i < 8; ++i) ones8[i] = (short)0x3F80;   // bf16 1.0

    f32x4 accLo[4];
    #pragma unroll
    for (int i = 0; i < 4; ++i) accLo[i] = (f32x4){0.f, 0.f, 0.f, 0.f};
    f32x4 dLo = (f32x4){0.f, 0.f, 0.f, 0.f};

    auto compute = [&](const short* fb, int tt) {
        #pragma unroll
        for (int kc = 0; kc < 2; ++kc) {
            const float2v* ep2 = (const float2v*)&el_lds[tt * 64 + kc * 32 + l4 * 8];
            uint32_t mLo = mbytes[moff_lo + tt * 8 + kc * 4 + l4];
            short8 aLo;
            #pragma unroll
            for (int jj = 0; jj < 4; ++jj) {
                float2v e2 = ep2[jj];
                float2v arg = __builtin_elementwise_max(e2 + c1s, e2 * k02 + c2s);
                float p0 = ((mLo >> (2 * jj)) & 1u)     ? fast_exp2(arg.x) : 0.f;
                float p1 = ((mLo >> (2 * jj + 1)) & 1u) ? fast_exp2(arg.y) : 0.f;
                aLo[2 * jj]     = f2bf(p0);
                aLo[2 * jj + 1] = f2bf(p1);
            }
            const int fo = (kc * 4 + l4) * 512 + l15 * 8;
            short8 bw0 = *(const short8*)(fb + fo);
            short8 bw1 = *(const short8*)(fb + fo + 128);
            short8 bw2 = *(const short8*)(fb + fo + 256);
            short8 bw3 = *(const short8*)(fb + fo + 384);
            __builtin_amdgcn_s_setprio(1);
            accLo[0] = __builtin_amdgcn_mfma_f32_16x16x32_bf16(aLo, bw0, accLo[0], 0, 0, 0);
            accLo[1] = __builtin_amdgcn_mfma_f32_16x16x32_bf16(aLo, bw1, accLo[1], 0, 0, 0);
            accLo[2] = __builtin_amdgcn_mfma_f32_16x16x32_bf16(aLo, bw2, accLo[2], 0, 0, 0);
            accLo[3] = __builtin_amdgcn_mfma_f32_16x16x32_bf16(aLo, bw3, accLo[3], 0, 0, 0);
            dLo      = __builtin_amdgcn_mfma_f32_16x16x32_bf16(aLo, ones8, dLo, 0, 0, 0);
            __builtin_amdgcn_s_setprio(0);
        }
    };

    short8 Ba, Bb;
    #pragma unroll 1
    for (int tt = 0; tt < 16; tt += 2) {
        // ---- even iteration tt ----
        if (tt + 2 < 16) {                  // issue loads for tile tt+2
            Ba = *(const short8*)(gsrc + (tt + 2) * 4096 + tid * 8);
            Bb = *(const short8*)(gsrc + (tt + 2) * 4096 + 2048 + tid * 8);
            __builtin_amdgcn_sched_barrier(0);
        }
        compute(f_lds[tt % 3], tt);
        {   // land tile tt+1 (loaded one full iteration ago)
            short* dst = f_lds[(tt + 1) % 3];
            *(short8*)&dst[tid * 8] = Aa;
            *(short8*)&dst[2048 + tid * 8] = Ab;
        }
        __syncthreads();
        // ---- odd iteration tt+1 ----
        if (tt + 3 < 16) {                  // issue loads for tile tt+3
            Aa = *(const short8*)(gsrc + (tt + 3) * 4096 + tid * 8);
            Ab = *(const short8*)(gsrc + (tt + 3) * 4096 + 2048 + tid * 8);
            __builtin_amdgcn_sched_barrier(0);
        }
        compute(f_lds[(tt + 1) % 3], tt + 1);
        if (tt + 2 < 16) {                  // land tile tt+2
            short* dst = f_lds[(tt + 2) % 3];
            *(short8*)&dst[tid * 8] = Ba;
            *(short8*)&dst[2048 + tid * 8] = Bb;
            __syncthreads();
        }
    }

    // ---- epilogue: normalize, +res, +bias, (ELU), store bf16 in place ----
    float rcpLo[4];
    #pragma unroll
    for (int r = 0; r < 4; ++r)
        rcpLo[r] = 1.f / fmaxf(dLo[r], 1e-9f);     // jnp.clip(sum, 1e-9)
    #pragma unroll
    for (int dt = 0; dt < 4; ++dt) {
        const int d = dt * 16 + l15;
        const float bv = bias[h * 64 + d];
        #pragma unroll
        for (int r = 0; r < 4; ++r) {
            const int vl = v0 + wid * 16 + l4 * 4 + r;
            const size_t rowL = (bN + vl) * 256 + h * 64 + d;
            float ov = accLo[dt][r] * rcpLo[r] + bf2f(fea[rowL]) + bv;
            if (ELU_ON) ov = ov > 0.f ? ov : __expf(ov) - 1.f;
            fea[rowL] = f2bf(ov);
        }
    }
}

// ---------------- K5: mean over heads (bf16 in) -> d_out fp32, 8-wide ----------------
__global__ __launch_bounds__(256) void k_headmean(
    const short* __restrict__ fea, float* __restrict__ outp)
{
    const int i = (blockIdx.x * 256 + threadIdx.x) * 8;   // over B*N*64, 8 d's/thread
    const int d0 = i & 63;
    const size_t node = (size_t)(i >> 6);
    const short* p = fea + node * 256 + d0;
    short8 h0 = *(const short8*)(p);
    short8 h1 = *(const short8*)(p + 64);
    short8 h2 = *(const short8*)(p + 128);
    short8 h3 = *(const short8*)(p + 192);
    float4 o0, o1;
    #pragma unroll
    for (int j = 0; j < 4; ++j) {
        float v = 0.25f * (bf2f(h0[j]) + bf2f(h1[j]) + bf2f(h2[j]) + bf2f(h3[j]));
        (&o0.x)[j] = v;
    }
    #pragma unroll
    for (int j = 0; j < 4; ++j) {
        float v = 0.25f * (bf2f(h0[4 + j]) + bf2f(h1[4 + j]) + bf2f(h2[4 + j]) + bf2f(h3[4 + j]));
        (&o1.x)[j] = v;
    }
    *(float4*)(outp + i) = o0;
    *(float4*)(outp + i + 4) = o1;
}

extern "C" void kernel_launch(void* const* d_in, const int* in_sizes, int n_in,
                              void* d_out, int out_size, void* d_ws, size_t ws_size,
                              hipStream_t stream) {
    const float* seg = (const float*)d_in[0];
    const float* adj = (const float*)d_in[1];
    const float* W0  = (const float*)d_in[2];
    const float* al0 = (const float*)d_in[3];
    const float* ar0 = (const float*)d_in[4];
    const float* rW0 = (const float*)d_in[5];
    const float* b0  = (const float*)d_in[6];
    const float* W1  = (const float*)d_in[7];
    const float* al1 = (const float*)d_in[8];
    const float* ar1 = (const float*)d_in[9];
    const float* rW1 = (const float*)d_in[10];
    const float* b1  = (const float*)d_in[11];
    float* out = (float*)d_out;

    char* ws = (char*)d_ws;
    size_t off = 0;
    uint64_t* mask  = (uint64_t*)ws;                 // 2 MB (dead after k_maskT)
    off += (size_t)BB * NN * 16 * 8;
    uint64_t* maskT = (uint64_t*)(ws + off); off += (size_t)BB * NN * 16 * 8;  // 2 MB
    short* ftb = (short*)(ws + off); off += (size_t)BB * 256 * NN * 2;         // 8 MB
    short* fea = (short*)(ws + off); off += (size_t)BB * NN * 256 * 2;         // 8 MB
    short* xb0 = (short*)(ws + off); off += (size_t)BB * NN * 64 * 2;          // 2 MB
    short* Wt0  = (short*)(ws + off); off += 256 * 64 * 2;
    short* rWt0 = (short*)(ws + off); off += 256 * 64 * 2;
    short* Wt1  = (short*)(ws + off); off += 256 * 256 * 2;
    short* rWt1 = (short*)(ws + off); off += 256 * 256 * 2;
    // el/er reuse the dead `mask` region (mask consumed by k_maskT)
    char* r0 = (char*)mask;
    float* el   = (float*)r0;                 r0 += (size_t)BB * 4 * NN * 4;
    float* er   = (float*)r0;                 r0 += (size_t)BB * 4 * NN * 4;

    k_topk_mask<<<4096 + 1664, 256, 0, stream>>>(adj, mask, W0, rW0, W1, rW1, seg,
                                                 Wt0, rWt0, Wt1, rWt1, xb0);
    k_maskT<<<1024, 256, 0, stream>>>(mask, maskT);

    // layer 0 (K=64)
    k_features_mfma<64><<<BB * NN / 32, 256, 0, stream>>>(xb0, Wt0, rWt0, al0, ar0,
                                                          ftb, fea, el, er);
    k_attn<1><<<1024, 256, 0, stream>>>(ftb, el, er, maskT, b0, fea);
    // layer 1 (K=256): x = fea in-place (x fully LDS-resident before fea write)
    k_features_mfma<256><<<BB * NN / 32, 256, 0, stream>>>(fea, Wt1, rWt1, al1, ar1,
                                                           ftb, fea, el, er);
    k_attn<0><<<1024, 256, 0, stream>>>(ftb, el, er, maskT, b1, fea);

    k_headmean<<<BB * NN * 64 / 2048, 256, 0, stream>>>(fea, out);
}

// Round 14
// 148.582 us; speedup vs baseline: 1.0379x; 1.0379x over previous
//
#include <hip/hip_runtime.h>
#include <hip/hip_bf16.h>
#include <stdint.h>

#define BB   16
#define NN   1024
#define KSEL 170   // (32*32)/6
#define LOG2E 1.4426950408889634f

typedef __attribute__((ext_vector_type(8))) short short8;
typedef __attribute__((ext_vector_type(4))) short short4v;
typedef __attribute__((ext_vector_type(4))) float f32x4;
typedef __attribute__((ext_vector_type(2))) float float2v;

static __device__ __forceinline__ short f2bf(float x) {
    __hip_bfloat16 h = __float2bfloat16(x);
    return *reinterpret_cast<short*>(&h);
}
static __device__ __forceinline__ float bf2f(short x) {
    uint32_t u = ((uint32_t)(uint16_t)x) << 16;
    return __uint_as_float(u);
}
static __device__ __forceinline__ float fast_exp2(float x) {
    float r; asm("v_exp_f32 %0, %1" : "=v"(r) : "v"(x)); return r;
}

// ---------------- K1: exact k-th-largest per row (one row/wave) + fused prep ---------
// 2 radix passes over 4 SUB-histograms/wave (16-lane groups -> 4x less same-bin atomic
// serialization) + wave-uniform survivor max-extraction. Exact for ties.
// blocks [0,4096): one row per wave; blocks [4096,5760): independent prep work.
__global__ __launch_bounds__(256) void k_topk_mask(
    const float* __restrict__ adj, uint64_t* __restrict__ mask,
    const float* __restrict__ W0, const float* __restrict__ rW0,
    const float* __restrict__ W1, const float* __restrict__ rW1,
    const float* __restrict__ seg,
    short* __restrict__ Wt0, short* __restrict__ rWt0,
    short* __restrict__ Wt1, short* __restrict__ rWt1,
    short* __restrict__ xb0)
{
    const int bid = blockIdx.x, t = threadIdx.x;
    if (bid >= 4096) {                                 // ---- prep roles ----
        const int pid = bid - 4096;
        if (pid < 64) {                  // Wt0 [256][64]
            int idx = pid * 256 + t;
            int o = idx >> 6, k = idx & 63;
            Wt0[idx] = f2bf(W0[(size_t)k * 256 + o]);
        } else if (pid < 128) {          // rWt0 [256][64]
            int idx = (pid - 64) * 256 + t;
            int o = idx >> 6, k = idx & 63;
            rWt0[idx] = f2bf(rW0[(size_t)k * 256 + o]);
        } else if (pid < 384) {          // Wt1 [256][256]
            int idx = (pid - 128) * 256 + t;
            int o = idx >> 8, k = idx & 255;
            Wt1[idx] = f2bf(W1[(size_t)k * 256 + o]);
        } else if (pid < 640) {          // rWt1 [256][256]
            int idx = (pid - 384) * 256 + t;
            int o = idx >> 8, k = idx & 255;
            rWt1[idx] = f2bf(rW1[(size_t)k * 256 + o]);
        } else {                         // seg fp32 -> bf16 (1M elems, 4/thread)
            int i = ((pid - 640) * 256 + t) * 4;
            float4 v = *(const float4*)(seg + i);
            short4v o4;
            o4[0] = f2bf(v.x); o4[1] = f2bf(v.y); o4[2] = f2bf(v.z); o4[3] = f2bf(v.w);
            *(short4v*)(xb0 + i) = o4;
        }
        return;
    }

    const int wid = t >> 6, lane = t & 63;
    const int row = bid * 4 + wid;                     // b*N + u
    const float* a = adj + (size_t)row * NN;
    __shared__ uint32_t hist[4][4][256];               // [wave][sub][bin]
    uint32_t* h = &hist[wid][0][0];
    uint32_t* hs = &hist[wid][lane >> 4][0];           // this lane's sub-histogram

    uint32_t key[16];
    #pragma unroll
    for (int j = 0; j < 16; ++j) {
        uint32_t u = __float_as_uint(a[lane + j * 64]);
        key[j] = u ^ ((u >> 31) ? 0xFFFFFFFFu : 0x80000000u);   // order-preserving map
    }

    uint32_t prefix = 0u, kk = KSEL;
    #pragma unroll
    for (int pass = 0; pass < 2; ++pass) {
        const int shift = 24 - 8 * pass;
        const uint32_t hi_mask = pass ? 0xFF000000u : 0u;
        #pragma unroll
        for (int s4 = 0; s4 < 4; ++s4)
            *(uint4*)&h[s4 * 256 + lane * 4] = make_uint4(0u, 0u, 0u, 0u);
        __builtin_amdgcn_wave_barrier();
        #pragma unroll
        for (int j = 0; j < 16; ++j)
            if ((key[j] & hi_mask) == prefix)
                atomicAdd(&hs[(key[j] >> shift) & 255], 1u);
        __builtin_amdgcn_wave_barrier();
        uint4 c0 = *(const uint4*)&h[lane * 4];        // bins 4L..4L+3, sub 0..3
        uint4 c1 = *(const uint4*)&h[256 + lane * 4];
        uint4 c2 = *(const uint4*)&h[512 + lane * 4];
        uint4 c3 = *(const uint4*)&h[768 + lane * 4];
        uint4 c4;
        c4.x = c0.x + c1.x + c2.x + c3.x;
        c4.y = c0.y + c1.y + c2.y + c3.y;
        c4.z = c0.z + c1.z + c2.z + c3.z;
        c4.w = c0.w + c1.w + c2.w + c3.w;
        const uint32_t T = c4.x + c4.y + c4.z + c4.w;
        uint32_t s = T;
        #pragma unroll
        for (int off = 1; off < 64; off <<= 1) {       // inclusive suffix sum over lanes
            uint32_t v = __shfl_down(s, off);
            s += (lane + off < 64) ? v : 0u;
        }
        const uint32_t E = s - T;                      // sum over lanes above
        const uint32_t s3 = c4.w;
        const uint32_t s2 = c4.z + s3;
        const uint32_t s1 = c4.y + s2;
        const uint32_t s0 = c4.x + s1;
        const uint32_t ci[4] = {c4.x, c4.y, c4.z, c4.w};
        const uint32_t si[4] = {s0, s1, s2, s3};
        uint32_t found = 0u, nb = 0u, nk = 0u;
        #pragma unroll
        for (int i = 0; i < 4; ++i) {
            uint32_t incl = E + si[i];                 // count of keys in bins >= this
            uint32_t excl = incl - ci[i];
            if (excl < kk && kk <= incl) { found = 1u; nb = (uint32_t)(lane * 4 + i); nk = kk - excl; }
        }
        uint64_t bal = __ballot(found != 0u);
        int wl = __ffsll((unsigned long long)bal) - 1; // exactly one winner
        prefix = prefix | ((uint32_t)__shfl((int)nb, wl) << shift);
        kk = (uint32_t)__shfl((int)nk, wl);
    }

    // ---- survivors share the 16-bit prefix; select kk-th largest exactly ----
    uint32_t sv[16];
    #pragma unroll
    for (int j = 0; j < 16; ++j)
        sv[j] = ((key[j] ^ prefix) >> 16) == 0u ? key[j] : 0u;   // 0 = sentinel

    uint32_t thr_key;
    for (;;) {
        uint32_t m = 0u;
        #pragma unroll
        for (int j = 0; j < 16; ++j) m = m > sv[j] ? m : sv[j];
        #pragma unroll
        for (int off = 1; off < 64; off <<= 1) {       // butterfly max -> uniform
            uint32_t v = __shfl_xor(m, off);
            m = m > v ? m : v;
        }
        if (m == 0u) { thr_key = 0u; break; }          // degenerate: thr = min key
        uint32_t c = 0u;
        #pragma unroll
        for (int j = 0; j < 16; ++j) c += (sv[j] == m) ? 1u : 0u;
        #pragma unroll
        for (int off = 1; off < 64; off <<= 1)
            c += __shfl_xor(c, off);                   // uniform count of == m
        if (kk <= c) { thr_key = m; break; }
        kk -= c;
        #pragma unroll
        for (int j = 0; j < 16; ++j) if (sv[j] == m) sv[j] = 0u;
    }

    #pragma unroll
    for (int j = 0; j < 16; ++j) {
        bool pred = (key[j] >= thr_key) && (key[j] > 0x80000000u);   // adj>=thr && adj>0
        uint64_t bal = __ballot(pred);
        if (lane == 0) mask[(size_t)row * 16 + j] = bal;
    }
}

// ---------------- K2: MFMA features — 32 nodes/block, 1 head/wave --------------------
// Blocks [nfeat, nfeat+1024) of the LAYER-0 launch run the 64x64 mask bit-transpose
// (independent of feature work; fused to save a launch).
template<int K>
__global__ __launch_bounds__(256, 2) void k_features_mfma(
    const short* __restrict__ xb,   // [B*N][K] bf16 row-major
    const short* __restrict__ Wt,   // [256][K] bf16
    const short* __restrict__ rWt,  // [256][K] bf16
    const float* __restrict__ al,   // [256]
    const float* __restrict__ ar,   // [256]
    short* __restrict__ ft,         // tiled transposed features [bh][ut16][g8][d64][ui8]
    short* __restrict__ fea,        // [B*N][256] bf16: res written here (may alias xb)
    float* __restrict__ el_t,       // [(b*4+h)][NN] scaled by LOG2E
    float* __restrict__ er_t,       // [(b*4+h)][NN] scaled by LOG2E
    const uint64_t* __restrict__ mask, uint64_t* __restrict__ maskT, int nfeat)
{
    const int bid = blockIdx.x;
    const int tid = threadIdx.x;
    if (bid >= nfeat) {                          // ---- fused maskT tiles ----
        const int tile = (bid - nfeat) * 4 + (tid >> 6);   // b*256 + uw*16 + vw
        const int lane = tid & 63;
        const int b  = tile >> 8;
        const int uw = (tile >> 4) & 15;
        const int vw = tile & 15;
        const size_t bN = (size_t)b * NN;
        uint64_t w = mask[(bN + uw * 64 + lane) * 16 + vw];
        uint64_t r_out = 0;
        #pragma unroll
        for (int j = 0; j < 64; ++j) {
            uint64_t r = __ballot((w >> j) & 1ull);
            if (lane == j) r_out = r;
        }
        maskT[(bN + vw * 64 + lane) * 16 + uw] = r_out;
        return;
    }

    const int lane = tid & 63, hh = tid >> 6;
    const int l15 = lane & 15, l4 = lane >> 4;
    const int n0 = bid * 32;                     // block's 32-node strip
    const int b_idx = n0 >> 10;                  // NN = 1024
    const int nloc = n0 & (NN - 1);
    const int bh = b_idx * 4 + hh;
    const int XP = K + 8;                        // padded LDS row stride (shorts)

    __shared__ short x_lds[32 * (K + 8)];

    const int CH = K / 8;                        // short8 chunks per row
    #pragma unroll
    for (int c = tid; c < 32 * CH; c += 256) {
        const int row = c / CH, col = c - row * CH;
        *(short8*)&x_lds[row * XP + col * 8] =
            *(const short8*)(xb + ((size_t)n0 + row) * K + col * 8);
    }
    __syncthreads();

    const short* wbase = Wt  + (size_t)(hh * 64 + l15) * K + l4 * 8;
    const short* rbase = rWt + (size_t)(hh * 64 + l15) * K + l4 * 8;
    const size_t qs = (size_t)16 * K;

    f32x4 accf[2][4], accr[2][4];
    #pragma unroll
    for (int s = 0; s < 2; ++s)
        #pragma unroll
        for (int q = 0; q < 4; ++q) {
            accf[s][q] = (f32x4){0.f, 0.f, 0.f, 0.f};
            accr[s][q] = (f32x4){0.f, 0.f, 0.f, 0.f};
        }

    short8 bufW[2][4], bufR[2][4];
    #pragma unroll
    for (int q = 0; q < 4; ++q) {
        bufW[0][q] = *(const short8*)(wbase + q * qs);
        bufR[0][q] = *(const short8*)(rbase + q * qs);
    }

    #pragma unroll
    for (int ks = 0; ks < K / 32; ++ks) {
        const int cur = ks & 1, nxt = cur ^ 1;
        if (ks + 1 < K / 32) {                   // prefetch next ks weight fragments
            #pragma unroll
            for (int q = 0; q < 4; ++q) {
                bufW[nxt][q] = *(const short8*)(wbase + q * qs + (ks + 1) * 32);
                bufR[nxt][q] = *(const short8*)(rbase + q * qs + (ks + 1) * 32);
            }
            __builtin_amdgcn_sched_barrier(0);   // pin load-issue before MFMA block
        }
        short8 x0 = *(const short8*)&x_lds[l15 * XP + ks * 32 + l4 * 8];
        short8 x1 = *(const short8*)&x_lds[(16 + l15) * XP + ks * 32 + l4 * 8];
        #pragma unroll
        for (int q = 0; q < 4; ++q) {
            accf[0][q] = __builtin_amdgcn_mfma_f32_16x16x32_bf16(x0, bufW[cur][q], accf[0][q], 0, 0, 0);
            accf[1][q] = __builtin_amdgcn_mfma_f32_16x16x32_bf16(x1, bufW[cur][q], accf[1][q], 0, 0, 0);
            accr[0][q] = __builtin_amdgcn_mfma_f32_16x16x32_bf16(bufR[cur][q], x0, accr[0][q], 0, 0, 0);
            accr[1][q] = __builtin_amdgcn_mfma_f32_16x16x32_bf16(bufR[cur][q], x1, accr[1][q], 0, 0, 0);
        }
    }

    #pragma unroll
    for (int s = 0; s < 2; ++s) {
        const int nl = nloc + s * 16;
        #pragma unroll
        for (int q = 0; q < 4; ++q) {
            short4v pk;
            #pragma unroll
            for (int r = 0; r < 4; ++r) pk[r] = f2bf(accf[s][q][r]);
            const int dl = q * 16 + l15;         // head-local d
            const size_t idx = ((size_t)bh << 16)
                             + (size_t)(nl >> 6) * 4096
                             + (size_t)(((nl & 63) >> 3) + (l4 >> 1)) * 512
                             + (size_t)dl * 8 + (l4 & 1) * 4;
            *(short4v*)(ft + idx) = pk;
        }
        float elv[4] = {0.f, 0.f, 0.f, 0.f}, erv[4] = {0.f, 0.f, 0.f, 0.f};
        #pragma unroll
        for (int q = 0; q < 4; ++q) {
            const float alv = al[hh * 64 + q * 16 + l15];
            const float arv = ar[hh * 64 + q * 16 + l15];
            #pragma unroll
            for (int r = 0; r < 4; ++r) {
                elv[r] = fmaf(accf[s][q][r], alv, elv[r]);
                erv[r] = fmaf(accf[s][q][r], arv, erv[r]);
            }
        }
        #pragma unroll
        for (int r = 0; r < 4; ++r) {
            #pragma unroll
            for (int off = 1; off < 16; off <<= 1) {
                elv[r] += __shfl_xor(elv[r], off);
                erv[r] += __shfl_xor(erv[r], off);
            }
        }
        if (l15 == 0) {                          // 4 lanes (l4=0..3), rows nl+l4*4+r
            float4 e4, r4;
            e4.x = elv[0] * LOG2E; e4.y = elv[1] * LOG2E;
            e4.z = elv[2] * LOG2E; e4.w = elv[3] * LOG2E;
            r4.x = erv[0] * LOG2E; r4.y = erv[1] * LOG2E;
            r4.z = erv[2] * LOG2E; r4.w = erv[3] * LOG2E;
            *(float4*)(el_t + (size_t)bh * NN + nl + l4 * 4) = e4;
            *(float4*)(er_t + (size_t)bh * NN + nl + l4 * 4) = r4;
        }
        #pragma unroll
        for (int q = 0; q < 4; ++q) {
            short4v pk;
            #pragma unroll
            for (int r = 0; r < 4; ++r) pk[r] = f2bf(accr[s][q][r]);
            *(short4v*)(fea + ((size_t)n0 + s * 16 + l15) * 256 + hh * 64 + q * 16 + l4 * 4) = pk;
        }
    }
}

// ---------------- K4: masked softmax + MFMA PV + residual + bias (+ELU) --------------
// 4 waves x 16 v; f-tile TRIPLE-buffered in LDS, 2-deep prefetch.
template<int ELU_ON>
__global__ __launch_bounds__(256, 4) void k_attn(
    const short* __restrict__ ft,     // tiled [bh][ut16][g8][d64][ui8]
    const float* __restrict__ el_t,   // [(b*4+h)][NN] scaled
    const float* __restrict__ er_t,   // [(b*4+h)][NN] scaled
    const uint64_t* __restrict__ maskT,// [b*N + v][16] u-words
    const float* __restrict__ bias,   // [256]
    short* fea)                       // [B*N][256] bf16: res in, out in-place
{
    // XCD swizzle: 1024 blocks, 128 per XCD (8 full bh strips per XCD)
    const int id = blockIdx.x;
    const int swz = (id & 7) * 128 + (id >> 3);
    const int b  = swz >> 6;
    const int h  = (swz >> 4) & 3;
    const int vt = swz & 15;
    const int tid = threadIdx.x;
    const int lane = tid & 63, wid = tid >> 6;
    const int l15 = lane & 15, l4 = lane >> 4;
    const int bh = b * 4 + h;
    const size_t bN = (size_t)b * NN;
    const int v0 = vt * 64;

    __shared__ __align__(16) short f_lds[3][4096];      // [buf][g*512 + d*8 + ui]
    __shared__ __align__(16) float el_lds[NN];
    __shared__ __align__(16) uint64_t m_lds[64 * 17];   // 136B row stride
    __shared__ float smax[4];

    const short* gsrc = ft + ((size_t)bh << 16);

    // ---- prologue staging: tile 0 -> buf0, el strip (+ block max), mask rows ----
    {
        short8 sa = *(const short8*)(gsrc + tid * 8);
        short8 sb = *(const short8*)(gsrc + 2048 + tid * 8);
        float4 ev4 = ((const float4*)(el_t + (size_t)bh * NN))[tid];
        ((float4*)el_lds)[tid] = ev4;
        float m = fmaxf(fmaxf(ev4.x, ev4.y), fmaxf(ev4.z, ev4.w));
        #pragma unroll
        for (int off = 32; off; off >>= 1) m = fmaxf(m, __shfl_xor(m, off));
        if (lane == 0) smax[wid] = m;
        #pragma unroll
        for (int i = 0; i < 4; ++i) {
            int idx = tid + i * 256;           // 1024 uint64 words
            m_lds[(idx >> 4) * 17 + (idx & 15)] =
                maskT[(bN + v0 + (idx >> 4)) * 16 + (idx & 15)];
        }
        *(short8*)&f_lds[0][tid * 8] = sa;
        *(short8*)&f_lds[0][2048 + tid * 8] = sb;
    }

    // prefetch tile 1 into register set A (lands during barrier + constants)
    short8 Aa = *(const short8*)(gsrc + 4096 + tid * 8);
    short8 Ab = *(const short8*)(gsrc + 4096 + 2048 + tid * 8);

    const int vlo = wid * 16 + l15;
    const float er_lo = er_t[(size_t)bh * NN + v0 + vlo];

    __syncthreads();

    const float emx = fmaxf(fmaxf(smax[0], smax[1]), fmaxf(smax[2], smax[3]));
    const float e0 = emx + er_lo;
    const float cv_lo = fmaxf(e0, 0.2f * e0);    // lrelu monotone -> valid shift
    const float c1_lo = er_lo - cv_lo, c2_lo = 0.2f * er_lo - cv_lo;
    const float2v c1s = {c1_lo, c1_lo};
    const float2v c2s = {c2_lo, c2_lo};
    const float2v k02 = {0.2f, 0.2f};

    const uint8_t* mbytes = (const uint8_t*)m_lds;
    const int moff_lo = vlo * 136;

    short8 ones8;
    #pragma unroll
    for (int i = 0; i < 8; ++i) ones8[i] = (short)0x3F80;   // bf16 1.0

    f32x4 accLo[4];
    #pragma unroll
    for (int i = 0; i < 4; ++i) accLo[i] = (f32x4){0.f, 0.f, 0.f, 0.f};
    f32x4 dLo = (f32x4){0.f, 0.f, 0.f, 0.f};

    auto compute = [&](const short* fb, int tt) {
        #pragma unroll
        for (int kc = 0; kc < 2; ++kc) {
            const float2v* ep2 = (const float2v*)&el_lds[tt * 64 + kc * 32 + l4 * 8];
            uint32_t mLo = mbytes[moff_lo + tt * 8 + kc * 4 + l4];
            short8 aLo;
            #pragma unroll
            for (int jj = 0; jj < 4; ++jj) {
                float2v e2 = ep2[jj];
                float2v arg = __builtin_elementwise_max(e2 + c1s, e2 * k02 + c2s);
                float p0 = ((mLo >> (2 * jj)) & 1u)     ? fast_exp2(arg.x) : 0.f;
                float p1 = ((mLo >> (2 * jj + 1)) & 1u) ? fast_exp2(arg.y) : 0.f;
                aLo[2 * jj]     = f2bf(p0);
                aLo[2 * jj + 1] = f2bf(p1);
            }
            const int fo = (kc * 4 + l4) * 512 + l15 * 8;
            short8 bw0 = *(const short8*)(fb + fo);
            short8 bw1 = *(const short8*)(fb + fo + 128);
            short8 bw2 = *(const short8*)(fb + fo + 256);
            short8 bw3 = *(const short8*)(fb + fo + 384);
            __builtin_amdgcn_s_setprio(1);
            accLo[0] = __builtin_amdgcn_mfma_f32_16x16x32_bf16(aLo, bw0, accLo[0], 0, 0, 0);
            accLo[1] = __builtin_amdgcn_mfma_f32_16x16x32_bf16(aLo, bw1, accLo[1], 0, 0, 0);
            accLo[2] = __builtin_amdgcn_mfma_f32_16x16x32_bf16(aLo, bw2, accLo[2], 0, 0, 0);
            accLo[3] = __builtin_amdgcn_mfma_f32_16x16x32_bf16(aLo, bw3, accLo[3], 0, 0, 0);
            dLo      = __builtin_amdgcn_mfma_f32_16x16x32_bf16(aLo, ones8, dLo, 0, 0, 0);
            __builtin_amdgcn_s_setprio(0);
        }
    };

    short8 Ba, Bb;
    #pragma unroll 1
    for (int tt = 0; tt < 16; tt += 2) {
        // ---- even iteration tt ----
        if (tt + 2 < 16) {                  // issue loads for tile tt+2
            Ba = *(const short8*)(gsrc + (tt + 2) * 4096 + tid * 8);
            Bb = *(const short8*)(gsrc + (tt + 2) * 4096 + 2048 + tid * 8);
            __builtin_amdgcn_sched_barrier(0);
        }
        compute(f_lds[tt % 3], tt);
        {   // land tile tt+1 (loaded one full iteration ago)
            short* dst = f_lds[(tt + 1) % 3];
            *(short8*)&dst[tid * 8] = Aa;
            *(short8*)&dst[2048 + tid * 8] = Ab;
        }
        __syncthreads();
        // ---- odd iteration tt+1 ----
        if (tt + 3 < 16) {                  // issue loads for tile tt+3
            Aa = *(const short8*)(gsrc + (tt + 3) * 4096 + tid * 8);
            Ab = *(const short8*)(gsrc + (tt + 3) * 4096 + 2048 + tid * 8);
            __builtin_amdgcn_sched_barrier(0);
        }
        compute(f_lds[(tt + 1) % 3], tt + 1);
        if (tt + 2 < 16) {                  // land tile tt+2
            short* dst = f_lds[(tt + 2) % 3];
            *(short8*)&dst[tid * 8] = Ba;
            *(short8*)&dst[2048 + tid * 8] = Bb;
            __syncthreads();
        }
    }

    // ---- epilogue: normalize, +res, +bias, (ELU), store bf16 in place ----
    float rcpLo[4];
    #pragma unroll
    for (int r = 0; r < 4; ++r)
        rcpLo[r] = 1.f / fmaxf(dLo[r], 1e-9f);     // jnp.clip(sum, 1e-9)
    #pragma unroll
    for (int dt = 0; dt < 4; ++dt) {
        const int d = dt * 16 + l15;
        const float bv = bias[h * 64 + d];
        #pragma unroll
        for (int r = 0; r < 4; ++r) {
            const int vl = v0 + wid * 16 + l4 * 4 + r;
            const size_t rowL = (bN + vl) * 256 + h * 64 + d;
            float ov = accLo[dt][r] * rcpLo[r] + bf2f(fea[rowL]) + bv;
            if (ELU_ON) ov = ov > 0.f ? ov : __expf(ov) - 1.f;
            fea[rowL] = f2bf(ov);
        }
    }
}

// ---------------- K5: mean over heads (bf16 in) -> d_out fp32, 8-wide ----------------
__global__ __launch_bounds__(256) void k_headmean(
    const short* __restrict__ fea, float* __restrict__ outp)
{
    const int i = (blockIdx.x * 256 + threadIdx.x) * 8;   // over B*N*64, 8 d's/thread
    const int d0 = i & 63;
    const size_t node = (size_t)(i >> 6);
    const short* p = fea + node * 256 + d0;
    short8 h0 = *(const short8*)(p);
    short8 h1 = *(const short8*)(p + 64);
    short8 h2 = *(const short8*)(p + 128);
    short8 h3 = *(const short8*)(p + 192);
    float4 o0, o1;
    #pragma unroll
    for (int j = 0; j < 4; ++j) {
        float v = 0.25f * (bf2f(h0[j]) + bf2f(h1[j]) + bf2f(h2[j]) + bf2f(h3[j]));
        (&o0.x)[j] = v;
    }
    #pragma unroll
    for (int j = 0; j < 4; ++j) {
        float v = 0.25f * (bf2f(h0[4 + j]) + bf2f(h1[4 + j]) + bf2f(h2[4 + j]) + bf2f(h3[4 + j]));
        (&o1.x)[j] = v;
    }
    *(float4*)(outp + i) = o0;
    *(float4*)(outp + i + 4) = o1;
}

extern "C" void kernel_launch(void* const* d_in, const int* in_sizes, int n_in,
                              void* d_out, int out_size, void* d_ws, size_t ws_size,
                              hipStream_t stream) {
    const float* seg = (const float*)d_in[0];
    const float* adj = (const float*)d_in[1];
    const float* W0  = (const float*)d_in[2];
    const float* al0 = (const float*)d_in[3];
    const float* ar0 = (const float*)d_in[4];
    const float* rW0 = (const float*)d_in[5];
    const float* b0  = (const float*)d_in[6];
    const float* W1  = (const float*)d_in[7];
    const float* al1 = (const float*)d_in[8];
    const float* ar1 = (const float*)d_in[9];
    const float* rW1 = (const float*)d_in[10];
    const float* b1  = (const float*)d_in[11];
    float* out = (float*)d_out;

    char* ws = (char*)d_ws;
    size_t off = 0;
    uint64_t* mask  = (uint64_t*)ws;                 // 2 MB (dead after maskT blocks)
    off += (size_t)BB * NN * 16 * 8;
    uint64_t* maskT = (uint64_t*)(ws + off); off += (size_t)BB * NN * 16 * 8;  // 2 MB
    short* ftb = (short*)(ws + off); off += (size_t)BB * 256 * NN * 2;         // 8 MB
    short* fea = (short*)(ws + off); off += (size_t)BB * NN * 256 * 2;         // 8 MB
    short* xb0 = (short*)(ws + off); off += (size_t)BB * NN * 64 * 2;          // 2 MB
    short* Wt0  = (short*)(ws + off); off += 256 * 64 * 2;
    short* rWt0 = (short*)(ws + off); off += 256 * 64 * 2;
    short* Wt1  = (short*)(ws + off); off += 256 * 256 * 2;
    short* rWt1 = (short*)(ws + off); off += 256 * 256 * 2;
    float* el   = (float*)(ws + off); off += (size_t)BB * 4 * NN * 4;
    float* er   = (float*)(ws + off); off += (size_t)BB * 4 * NN * 4;

    k_topk_mask<<<4096 + 1664, 256, 0, stream>>>(adj, mask, W0, rW0, W1, rW1, seg,
                                                 Wt0, rWt0, Wt1, rWt1, xb0);

    // layer 0 (K=64) + fused maskT (blocks 512..1535)
    k_features_mfma<64><<<512 + 1024, 256, 0, stream>>>(xb0, Wt0, rWt0, al0, ar0,
                                                        ftb, fea, el, er,
                                                        mask, maskT, 512);
    k_attn<1><<<1024, 256, 0, stream>>>(ftb, el, er, maskT, b0, fea);
    // layer 1 (K=256): x = fea in-place (x fully LDS-resident before fea write)
    k_features_mfma<256><<<512, 256, 0, stream>>>(fea, Wt1, rWt1, al1, ar1,
                                                  ftb, fea, el, er,
                                                  mask, maskT, 512);
    k_attn<0><<<1024, 256, 0, stream>>>(ftb, el, er, maskT, b1, fea);

    k_headmean<<<BB * NN * 64 / 2048, 256, 0, stream>>>(fea, out);
}

// Round 15
// 140.413 us; speedup vs baseline: 1.0983x; 1.0582x over previous
//
#include <hip/hip_runtime.h>
#include <hip/hip_bf16.h>
#include <stdint.h>

#define BB   16
#define NN   1024
#define KSEL 170   // (32*32)/6
#define LOG2E 1.4426950408889634f
#define HP   264   // padded sub-histogram stride: 264%32=8 -> each sub shifted 8 banks

typedef __attribute__((ext_vector_type(8))) short short8;
typedef __attribute__((ext_vector_type(4))) short short4v;
typedef __attribute__((ext_vector_type(4))) float f32x4;
typedef __attribute__((ext_vector_type(2))) float float2v;

static __device__ __forceinline__ short f2bf(float x) {
    __hip_bfloat16 h = __float2bfloat16(x);
    return *reinterpret_cast<short*>(&h);
}
static __device__ __forceinline__ float bf2f(short x) {
    uint32_t u = ((uint32_t)(uint16_t)x) << 16;
    return __uint_as_float(u);
}
static __device__ __forceinline__ float fast_exp2(float x) {
    float r; asm("v_exp_f32 %0, %1" : "=v"(r) : "v"(x)); return r;
}

// ---------------- K1: exact k-th-largest per row (one row/wave) + fused prep ---------
// 2 radix passes over 4 BANK-SHIFTED sub-histograms/wave (stride 264 words: sub s
// offset s*8 banks -> concentrated bins spread across banks) + survivor extraction.
// blocks [0,4096): one row per wave; blocks [4096,5760): independent prep work.
__global__ __launch_bounds__(256) void k_topk_mask(
    const float* __restrict__ adj, uint64_t* __restrict__ mask,
    const float* __restrict__ W0, const float* __restrict__ rW0,
    const float* __restrict__ W1, const float* __restrict__ rW1,
    const float* __restrict__ seg,
    short* __restrict__ Wt0, short* __restrict__ rWt0,
    short* __restrict__ Wt1, short* __restrict__ rWt1,
    short* __restrict__ xb0)
{
    const int bid = blockIdx.x, t = threadIdx.x;
    if (bid >= 4096) {                                 // ---- prep roles ----
        const int pid = bid - 4096;
        if (pid < 64) {                  // Wt0 [256][64]
            int idx = pid * 256 + t;
            int o = idx >> 6, k = idx & 63;
            Wt0[idx] = f2bf(W0[(size_t)k * 256 + o]);
        } else if (pid < 128) {          // rWt0 [256][64]
            int idx = (pid - 64) * 256 + t;
            int o = idx >> 6, k = idx & 63;
            rWt0[idx] = f2bf(rW0[(size_t)k * 256 + o]);
        } else if (pid < 384) {          // Wt1 [256][256]
            int idx = (pid - 128) * 256 + t;
            int o = idx >> 8, k = idx & 255;
            Wt1[idx] = f2bf(W1[(size_t)k * 256 + o]);
        } else if (pid < 640) {          // rWt1 [256][256]
            int idx = (pid - 384) * 256 + t;
            int o = idx >> 8, k = idx & 255;
            rWt1[idx] = f2bf(rW1[(size_t)k * 256 + o]);
        } else {                         // seg fp32 -> bf16 (1M elems, 4/thread)
            int i = ((pid - 640) * 256 + t) * 4;
            float4 v = *(const float4*)(seg + i);
            short4v o4;
            o4[0] = f2bf(v.x); o4[1] = f2bf(v.y); o4[2] = f2bf(v.z); o4[3] = f2bf(v.w);
            *(short4v*)(xb0 + i) = o4;
        }
        return;
    }

    const int wid = t >> 6, lane = t & 63;
    const int row = bid * 4 + wid;                     // b*N + u
    const float* a = adj + (size_t)row * NN;
    __shared__ uint32_t hist[4][4 * HP];               // [wave][sub*HP + bin]
    uint32_t* h = &hist[wid][0];
    uint32_t* hs = &hist[wid][(lane >> 4) * HP];       // this lane's sub-histogram

    uint32_t key[16];
    #pragma unroll
    for (int j = 0; j < 16; ++j) {
        uint32_t u = __float_as_uint(a[lane + j * 64]);
        key[j] = u ^ ((u >> 31) ? 0xFFFFFFFFu : 0x80000000u);   // order-preserving map
    }

    uint32_t prefix = 0u, kk = KSEL;
    #pragma unroll
    for (int pass = 0; pass < 2; ++pass) {
        const int shift = 24 - 8 * pass;
        const uint32_t hi_mask = pass ? 0xFF000000u : 0u;
        #pragma unroll
        for (int s4 = 0; s4 < 4; ++s4)
            *(uint4*)&h[s4 * HP + lane * 4] = make_uint4(0u, 0u, 0u, 0u);
        __builtin_amdgcn_wave_barrier();
        #pragma unroll
        for (int j = 0; j < 16; ++j)
            if ((key[j] & hi_mask) == prefix)
                atomicAdd(&hs[(key[j] >> shift) & 255], 1u);
        __builtin_amdgcn_wave_barrier();
        uint4 c0 = *(const uint4*)&h[lane * 4];        // bins 4L..4L+3, sub 0..3
        uint4 c1 = *(const uint4*)&h[HP + lane * 4];
        uint4 c2 = *(const uint4*)&h[2 * HP + lane * 4];
        uint4 c3 = *(const uint4*)&h[3 * HP + lane * 4];
        uint4 c4;
        c4.x = c0.x + c1.x + c2.x + c3.x;
        c4.y = c0.y + c1.y + c2.y + c3.y;
        c4.z = c0.z + c1.z + c2.z + c3.z;
        c4.w = c0.w + c1.w + c2.w + c3.w;
        const uint32_t T = c4.x + c4.y + c4.z + c4.w;
        uint32_t s = T;
        #pragma unroll
        for (int off = 1; off < 64; off <<= 1) {       // inclusive suffix sum over lanes
            uint32_t v = __shfl_down(s, off);
            s += (lane + off < 64) ? v : 0u;
        }
        const uint32_t E = s - T;                      // sum over lanes above
        const uint32_t s3 = c4.w;
        const uint32_t s2 = c4.z + s3;
        const uint32_t s1 = c4.y + s2;
        const uint32_t s0 = c4.x + s1;
        const uint32_t ci[4] = {c4.x, c4.y, c4.z, c4.w};
        const uint32_t si[4] = {s0, s1, s2, s3};
        uint32_t found = 0u, nb = 0u, nk = 0u;
        #pragma unroll
        for (int i = 0; i < 4; ++i) {
            uint32_t incl = E + si[i];                 // count of keys in bins >= this
            uint32_t excl = incl - ci[i];
            if (excl < kk && kk <= incl) { found = 1u; nb = (uint32_t)(lane * 4 + i); nk = kk - excl; }
        }
        uint64_t bal = __ballot(found != 0u);
        int wl = __ffsll((unsigned long long)bal) - 1; // exactly one winner
        prefix = prefix | ((uint32_t)__shfl((int)nb, wl) << shift);
        kk = (uint32_t)__shfl((int)nk, wl);
    }

    // ---- survivors share the 16-bit prefix; select kk-th largest exactly ----
    uint32_t sv[16];
    #pragma unroll
    for (int j = 0; j < 16; ++j)
        sv[j] = ((key[j] ^ prefix) >> 16) == 0u ? key[j] : 0u;   // 0 = sentinel

    uint32_t thr_key;
    for (;;) {
        uint32_t m = 0u;
        #pragma unroll
        for (int j = 0; j < 16; ++j) m = m > sv[j] ? m : sv[j];
        #pragma unroll
        for (int off = 1; off < 64; off <<= 1) {       // butterfly max -> uniform
            uint32_t v = __shfl_xor(m, off);
            m = m > v ? m : v;
        }
        if (m == 0u) { thr_key = 0u; break; }          // degenerate: thr = min key
        uint32_t c = 0u;
        #pragma unroll
        for (int j = 0; j < 16; ++j) c += (sv[j] == m) ? 1u : 0u;
        #pragma unroll
        for (int off = 1; off < 64; off <<= 1)
            c += __shfl_xor(c, off);                   // uniform count of == m
        if (kk <= c) { thr_key = m; break; }
        kk -= c;
        #pragma unroll
        for (int j = 0; j < 16; ++j) if (sv[j] == m) sv[j] = 0u;
    }

    #pragma unroll
    for (int j = 0; j < 16; ++j) {
        bool pred = (key[j] >= thr_key) && (key[j] > 0x80000000u);   // adj>=thr && adj>0
        uint64_t bal = __ballot(pred);
        if (lane == 0) mask[(size_t)row * 16 + j] = bal;
    }
}

// ---------------- K2: MFMA features — 32 nodes/block, 1 head/wave --------------------
// Blocks [nfeat, nfeat+1024) of the LAYER-0 launch run the 64x64 mask bit-transpose
// (independent of feature work; fused to save a launch).
template<int K>
__global__ __launch_bounds__(256, 2) void k_features_mfma(
    const short* __restrict__ xb,   // [B*N][K] bf16 row-major
    const short* __restrict__ Wt,   // [256][K] bf16
    const short* __restrict__ rWt,  // [256][K] bf16
    const float* __restrict__ al,   // [256]
    const float* __restrict__ ar,   // [256]
    short* __restrict__ ft,         // tiled transposed features [bh][ut16][g8][d64][ui8]
    short* __restrict__ fea,        // [B*N][256] bf16: res written here (may alias xb)
    float* __restrict__ el_t,       // [(b*4+h)][NN] scaled by LOG2E
    float* __restrict__ er_t,       // [(b*4+h)][NN] scaled by LOG2E
    const uint64_t* __restrict__ mask, uint64_t* __restrict__ maskT, int nfeat)
{
    const int bid = blockIdx.x;
    const int tid = threadIdx.x;
    if (bid >= nfeat) {                          // ---- fused maskT tiles ----
        const int tile = (bid - nfeat) * 4 + (tid >> 6);   // b*256 + uw*16 + vw
        const int lane = tid & 63;
        const int b  = tile >> 8;
        const int uw = (tile >> 4) & 15;
        const int vw = tile & 15;
        const size_t bN = (size_t)b * NN;
        uint64_t w = mask[(bN + uw * 64 + lane) * 16 + vw];
        uint64_t r_out = 0;
        #pragma unroll
        for (int j = 0; j < 64; ++j) {
            uint64_t r = __ballot((w >> j) & 1ull);
            if (lane == j) r_out = r;
        }
        maskT[(bN + vw * 64 + lane) * 16 + uw] = r_out;
        return;
    }

    const int lane = tid & 63, hh = tid >> 6;
    const int l15 = lane & 15, l4 = lane >> 4;
    const int n0 = bid * 32;                     // block's 32-node strip
    const int b_idx = n0 >> 10;                  // NN = 1024
    const int nloc = n0 & (NN - 1);
    const int bh = b_idx * 4 + hh;
    const int XP = K + 8;                        // padded LDS row stride (shorts)

    __shared__ short x_lds[32 * (K + 8)];

    const int CH = K / 8;                        // short8 chunks per row
    #pragma unroll
    for (int c = tid; c < 32 * CH; c += 256) {
        const int row = c / CH, col = c - row * CH;
        *(short8*)&x_lds[row * XP + col * 8] =
            *(const short8*)(xb + ((size_t)n0 + row) * K + col * 8);
    }
    __syncthreads();

    const short* wbase = Wt  + (size_t)(hh * 64 + l15) * K + l4 * 8;
    const short* rbase = rWt + (size_t)(hh * 64 + l15) * K + l4 * 8;
    const size_t qs = (size_t)16 * K;

    f32x4 accf[2][4], accr[2][4];
    #pragma unroll
    for (int s = 0; s < 2; ++s)
        #pragma unroll
        for (int q = 0; q < 4; ++q) {
            accf[s][q] = (f32x4){0.f, 0.f, 0.f, 0.f};
            accr[s][q] = (f32x4){0.f, 0.f, 0.f, 0.f};
        }

    short8 bufW[2][4], bufR[2][4];
    #pragma unroll
    for (int q = 0; q < 4; ++q) {
        bufW[0][q] = *(const short8*)(wbase + q * qs);
        bufR[0][q] = *(const short8*)(rbase + q * qs);
    }

    #pragma unroll
    for (int ks = 0; ks < K / 32; ++ks) {
        const int cur = ks & 1, nxt = cur ^ 1;
        if (ks + 1 < K / 32) {                   // prefetch next ks weight fragments
            #pragma unroll
            for (int q = 0; q < 4; ++q) {
                bufW[nxt][q] = *(const short8*)(wbase + q * qs + (ks + 1) * 32);
                bufR[nxt][q] = *(const short8*)(rbase + q * qs + (ks + 1) * 32);
            }
            __builtin_amdgcn_sched_barrier(0);   // pin load-issue before MFMA block
        }
        short8 x0 = *(const short8*)&x_lds[l15 * XP + ks * 32 + l4 * 8];
        short8 x1 = *(const short8*)&x_lds[(16 + l15) * XP + ks * 32 + l4 * 8];
        #pragma unroll
        for (int q = 0; q < 4; ++q) {
            accf[0][q] = __builtin_amdgcn_mfma_f32_16x16x32_bf16(x0, bufW[cur][q], accf[0][q], 0, 0, 0);
            accf[1][q] = __builtin_amdgcn_mfma_f32_16x16x32_bf16(x1, bufW[cur][q], accf[1][q], 0, 0, 0);
            accr[0][q] = __builtin_amdgcn_mfma_f32_16x16x32_bf16(bufR[cur][q], x0, accr[0][q], 0, 0, 0);
            accr[1][q] = __builtin_amdgcn_mfma_f32_16x16x32_bf16(bufR[cur][q], x1, accr[1][q], 0, 0, 0);
        }
    }

    #pragma unroll
    for (int s = 0; s < 2; ++s) {
        const int nl = nloc + s * 16;
        #pragma unroll
        for (int q = 0; q < 4; ++q) {
            short4v pk;
            #pragma unroll
            for (int r = 0; r < 4; ++r) pk[r] = f2bf(accf[s][q][r]);
            const int dl = q * 16 + l15;         // head-local d
            const size_t idx = ((size_t)bh << 16)
                             + (size_t)(nl >> 6) * 4096
                             + (size_t)(((nl & 63) >> 3) + (l4 >> 1)) * 512
                             + (size_t)dl * 8 + (l4 & 1) * 4;
            *(short4v*)(ft + idx) = pk;
        }
        float elv[4] = {0.f, 0.f, 0.f, 0.f}, erv[4] = {0.f, 0.f, 0.f, 0.f};
        #pragma unroll
        for (int q = 0; q < 4; ++q) {
            const float alv = al[hh * 64 + q * 16 + l15];
            const float arv = ar[hh * 64 + q * 16 + l15];
            #pragma unroll
            for (int r = 0; r < 4; ++r) {
                elv[r] = fmaf(accf[s][q][r], alv, elv[r]);
                erv[r] = fmaf(accf[s][q][r], arv, erv[r]);
            }
        }
        #pragma unroll
        for (int r = 0; r < 4; ++r) {
            #pragma unroll
            for (int off = 1; off < 16; off <<= 1) {
                elv[r] += __shfl_xor(elv[r], off);
                erv[r] += __shfl_xor(erv[r], off);
            }
        }
        if (l15 == 0) {                          // 4 lanes (l4=0..3), rows nl+l4*4+r
            float4 e4, r4;
            e4.x = elv[0] * LOG2E; e4.y = elv[1] * LOG2E;
            e4.z = elv[2] * LOG2E; e4.w = elv[3] * LOG2E;
            r4.x = erv[0] * LOG2E; r4.y = erv[1] * LOG2E;
            r4.z = erv[2] * LOG2E; r4.w = erv[3] * LOG2E;
            *(float4*)(el_t + (size_t)bh * NN + nl + l4 * 4) = e4;
            *(float4*)(er_t + (size_t)bh * NN + nl + l4 * 4) = r4;
        }
        #pragma unroll
        for (int q = 0; q < 4; ++q) {
            short4v pk;
            #pragma unroll
            for (int r = 0; r < 4; ++r) pk[r] = f2bf(accr[s][q][r]);
            *(short4v*)(fea + ((size_t)n0 + s * 16 + l15) * 256 + hh * 64 + q * 16 + l4 * 4) = pk;
        }
    }
}

// ---------------- K4: masked softmax + MFMA PV + residual + bias (+ELU) --------------
// 4 waves x 16 v; f-tile TRIPLE-buffered in LDS, 2-deep prefetch.
template<int ELU_ON>
__global__ __launch_bounds__(256, 4) void k_attn(
    const short* __restrict__ ft,     // tiled [bh][ut16][g8][d64][ui8]
    const float* __restrict__ el_t,   // [(b*4+h)][NN] scaled
    const float* __restrict__ er_t,   // [(b*4+h)][NN] scaled
    const uint64_t* __restrict__ maskT,// [b*N + v][16] u-words
    const float* __restrict__ bias,   // [256]
    short* fea)                       // [B*N][256] bf16: res in, out in-place
{
    // XCD swizzle: 1024 blocks, 128 per XCD (8 full bh strips per XCD)
    const int id = blockIdx.x;
    const int swz = (id & 7) * 128 + (id >> 3);
    const int b  = swz >> 6;
    const int h  = (swz >> 4) & 3;
    const int vt = swz & 15;
    const int tid = threadIdx.x;
    const int lane = tid & 63, wid = tid >> 6;
    const int l15 = lane & 15, l4 = lane >> 4;
    const int bh = b * 4 + h;
    const size_t bN = (size_t)b * NN;
    const int v0 = vt * 64;

    __shared__ __align__(16) short f_lds[3][4096];      // [buf][g*512 + d*8 + ui]
    __shared__ __align__(16) float el_lds[NN];
    __shared__ __align__(16) uint64_t m_lds[64 * 17];   // 136B row stride
    __shared__ float smax[4];

    const short* gsrc = ft + ((size_t)bh << 16);

    // ---- prologue staging: tile 0 -> buf0, el strip (+ block max), mask rows ----
    {
        short8 sa = *(const short8*)(gsrc + tid * 8);
        short8 sb = *(const short8*)(gsrc + 2048 + tid * 8);
        float4 ev4 = ((const float4*)(el_t + (size_t)bh * NN))[tid];
        ((float4*)el_lds)[tid] = ev4;
        float m = fmaxf(fmaxf(ev4.x, ev4.y), fmaxf(ev4.z, ev4.w));
        #pragma unroll
        for (int off = 32; off; off >>= 1) m = fmaxf(m, __shfl_xor(m, off));
        if (lane == 0) smax[wid] = m;
        #pragma unroll
        for (int i = 0; i < 4; ++i) {
            int idx = tid + i * 256;           // 1024 uint64 words
            m_lds[(idx >> 4) * 17 + (idx & 15)] =
                maskT[(bN + v0 + (idx >> 4)) * 16 + (idx & 15)];
        }
        *(short8*)&f_lds[0][tid * 8] = sa;
        *(short8*)&f_lds[0][2048 + tid * 8] = sb;
    }

    // prefetch tile 1 into register set A (lands during barrier + constants)
    short8 Aa = *(const short8*)(gsrc + 4096 + tid * 8);
    short8 Ab = *(const short8*)(gsrc + 4096 + 2048 + tid * 8);

    const int vlo = wid * 16 + l15;
    const float er_lo = er_t[(size_t)bh * NN + v0 + vlo];

    __syncthreads();

    const float emx = fmaxf(fmaxf(smax[0], smax[1]), fmaxf(smax[2], smax[3]));
    const float e0 = emx + er_lo;
    const float cv_lo = fmaxf(e0, 0.2f * e0);    // lrelu monotone -> valid shift
    const float c1_lo = er_lo - cv_lo, c2_lo = 0.2f * er_lo - cv_lo;
    const float2v c1s = {c1_lo, c1_lo};
    const float2v c2s = {c2_lo, c2_lo};
    const float2v k02 = {0.2f, 0.2f};

    const uint8_t* mbytes = (const uint8_t*)m_lds;
    const int moff_lo = vlo * 136;

    short8 ones8;
    #pragma unroll
    for (int i = 0; i < 8; ++i) ones8[i] = (short)0x3F80;   // bf16 1.0

    f32x4 accLo[4];
    #pragma unroll
    for (int i = 0; i < 4; ++i) accLo[i] = (f32x4){0.f, 0.f, 0.f, 0.f};
    f32x4 dLo = (f32x4){0.f, 0.f, 0.f, 0.f};

    auto compute = [&](const short* fb, int tt) {
        #pragma unroll
        for (int kc = 0; kc < 2; ++kc) {
            const float2v* ep2 = (const float2v*)&el_lds[tt * 64 + kc * 32 + l4 * 8];
            uint32_t mLo = mbytes[moff_lo + tt * 8 + kc * 4 + l4];
            short8 aLo;
            #pragma unroll
            for (int jj = 0; jj < 4; ++jj) {
                float2v e2 = ep2[jj];
                float2v arg = __builtin_elementwise_max(e2 + c1s, e2 * k02 + c2s);
                float p0 = ((mLo >> (2 * jj)) & 1u)     ? fast_exp2(arg.x) : 0.f;
                float p1 = ((mLo >> (2 * jj + 1)) & 1u) ? fast_exp2(arg.y) : 0.f;
                aLo[2 * jj]     = f2bf(p0);
                aLo[2 * jj + 1] = f2bf(p1);
            }
            const int fo = (kc * 4 + l4) * 512 + l15 * 8;
            short8 bw0 = *(const short8*)(fb + fo);
            short8 bw1 = *(const short8*)(fb + fo + 128);
            short8 bw2 = *(const short8*)(fb + fo + 256);
            short8 bw3 = *(const short8*)(fb + fo + 384);
            __builtin_amdgcn_s_setprio(1);
            accLo[0] = __builtin_amdgcn_mfma_f32_16x16x32_bf16(aLo, bw0, accLo[0], 0, 0, 0);
            accLo[1] = __builtin_amdgcn_mfma_f32_16x16x32_bf16(aLo, bw1, accLo[1], 0, 0, 0);
            accLo[2] = __builtin_amdgcn_mfma_f32_16x16x32_bf16(aLo, bw2, accLo[2], 0, 0, 0);
            accLo[3] = __builtin_amdgcn_mfma_f32_16x16x32_bf16(aLo, bw3, accLo[3], 0, 0, 0);
            dLo      = __builtin_amdgcn_mfma_f32_16x16x32_bf16(aLo, ones8, dLo, 0, 0, 0);
            __builtin_amdgcn_s_setprio(0);
        }
    };

    short8 Ba, Bb;
    #pragma unroll 1
    for (int tt = 0; tt < 16; tt += 2) {
        // ---- even iteration tt ----
        if (tt + 2 < 16) {                  // issue loads for tile tt+2
            Ba = *(const short8*)(gsrc + (tt + 2) * 4096 + tid * 8);
            Bb = *(const short8*)(gsrc + (tt + 2) * 4096 + 2048 + tid * 8);
            __builtin_amdgcn_sched_barrier(0);
        }
        compute(f_lds[tt % 3], tt);
        {   // land tile tt+1 (loaded one full iteration ago)
            short* dst = f_lds[(tt + 1) % 3];
            *(short8*)&dst[tid * 8] = Aa;
            *(short8*)&dst[2048 + tid * 8] = Ab;
        }
        __syncthreads();
        // ---- odd iteration tt+1 ----
        if (tt + 3 < 16) {                  // issue loads for tile tt+3
            Aa = *(const short8*)(gsrc + (tt + 3) * 4096 + tid * 8);
            Ab = *(const short8*)(gsrc + (tt + 3) * 4096 + 2048 + tid * 8);
            __builtin_amdgcn_sched_barrier(0);
        }
        compute(f_lds[(tt + 1) % 3], tt + 1);
        if (tt + 2 < 16) {                  // land tile tt+2
            short* dst = f_lds[(tt + 2) % 3];
            *(short8*)&dst[tid * 8] = Ba;
            *(short8*)&dst[2048 + tid * 8] = Bb;
            __syncthreads();
        }
    }

    // ---- epilogue: normalize, +res, +bias, (ELU), store bf16 in place ----
    float rcpLo[4];
    #pragma unroll
    for (int r = 0; r < 4; ++r)
        rcpLo[r] = 1.f / fmaxf(dLo[r], 1e-9f);     // jnp.clip(sum, 1e-9)
    #pragma unroll
    for (int dt = 0; dt < 4; ++dt) {
        const int d = dt * 16 + l15;
        const float bv = bias[h * 64 + d];
        #pragma unroll
        for (int r = 0; r < 4; ++r) {
            const int vl = v0 + wid * 16 + l4 * 4 + r;
            const size_t rowL = (bN + vl) * 256 + h * 64 + d;
            float ov = accLo[dt][r] * rcpLo[r] + bf2f(fea[rowL]) + bv;
            if (ELU_ON) ov = ov > 0.f ? ov : __expf(ov) - 1.f;
            fea[rowL] = f2bf(ov);
        }
    }
}

// ---------------- K5: mean over heads (bf16 in) -> d_out fp32, 8-wide ----------------
__global__ __launch_bounds__(256) void k_headmean(
    const short* __restrict__ fea, float* __restrict__ outp)
{
    const int i = (blockIdx.x * 256 + threadIdx.x) * 8;   // over B*N*64, 8 d's/thread
    const int d0 = i & 63;
    const size_t node = (size_t)(i >> 6);
    const short* p = fea + node * 256 + d0;
    short8 h0 = *(const short8*)(p);
    short8 h1 = *(const short8*)(p + 64);
    short8 h2 = *(const short8*)(p + 128);
    short8 h3 = *(const short8*)(p + 192);
    float4 o0, o1;
    #pragma unroll
    for (int j = 0; j < 4; ++j) {
        float v = 0.25f * (bf2f(h0[j]) + bf2f(h1[j]) + bf2f(h2[j]) + bf2f(h3[j]));
        (&o0.x)[j] = v;
    }
    #pragma unroll
    for (int j = 0; j < 4; ++j) {
        float v = 0.25f * (bf2f(h0[4 + j]) + bf2f(h1[4 + j]) + bf2f(h2[4 + j]) + bf2f(h3[4 + j]));
        (&o1.x)[j] = v;
    }
    *(float4*)(outp + i) = o0;
    *(float4*)(outp + i + 4) = o1;
}

extern "C" void kernel_launch(void* const* d_in, const int* in_sizes, int n_in,
                              void* d_out, int out_size, void* d_ws, size_t ws_size,
                              hipStream_t stream) {
    const float* seg = (const float*)d_in[0];
    const float* adj = (const float*)d_in[1];
    const float* W0  = (const float*)d_in[2];
    const float* al0 = (const float*)d_in[3];
    const float* ar0 = (const float*)d_in[4];
    const float* rW0 = (const float*)d_in[5];
    const float* b0  = (const float*)d_in[6];
    const float* W1  = (const float*)d_in[7];
    const float* al1 = (const float*)d_in[8];
    const float* ar1 = (const float*)d_in[9];
    const float* rW1 = (const float*)d_in[10];
    const float* b1  = (const float*)d_in[11];
    float* out = (float*)d_out;

    char* ws = (char*)d_ws;
    size_t off = 0;
    uint64_t* mask  = (uint64_t*)ws;                 // 2 MB (dead after maskT blocks)
    off += (size_t)BB * NN * 16 * 8;
    uint64_t* maskT = (uint64_t*)(ws + off); off += (size_t)BB * NN * 16 * 8;  // 2 MB
    short* ftb = (short*)(ws + off); off += (size_t)BB * 256 * NN * 2;         // 8 MB
    short* fea = (short*)(ws + off); off += (size_t)BB * NN * 256 * 2;         // 8 MB
    short* xb0 = (short*)(ws + off); off += (size_t)BB * NN * 64 * 2;          // 2 MB
    short* Wt0  = (short*)(ws + off); off += 256 * 64 * 2;
    short* rWt0 = (short*)(ws + off); off += 256 * 64 * 2;
    short* Wt1  = (short*)(ws + off); off += 256 * 256 * 2;
    short* rWt1 = (short*)(ws + off); off += 256 * 256 * 2;
    float* el   = (float*)(ws + off); off += (size_t)BB * 4 * NN * 4;
    float* er   = (float*)(ws + off); off += (size_t)BB * 4 * NN * 4;

    k_topk_mask<<<4096 + 1664, 256, 0, stream>>>(adj, mask, W0, rW0, W1, rW1, seg,
                                                 Wt0, rWt0, Wt1, rWt1, xb0);

    // layer 0 (K=64) + fused maskT (blocks 512..1535)
    k_features_mfma<64><<<512 + 1024, 256, 0, stream>>>(xb0, Wt0, rWt0, al0, ar0,
                                                        ftb, fea, el, er,
                                                        mask, maskT, 512);
    k_attn<1><<<1024, 256, 0, stream>>>(ftb, el, er, maskT, b0, fea);
    // layer 1 (K=256): x = fea in-place (x fully LDS-resident before fea write)
    k_features_mfma<256><<<512, 256, 0, stream>>>(fea, Wt1, rWt1, al1, ar1,
                                                  ftb, fea, el, er,
                                                  mask, maskT, 512);
    k_attn<0><<<1024, 256, 0, stream>>>(ftb, el, er, maskT, b1, fea);

    k_headmean<<<BB * NN * 64 / 2048, 256, 0, stream>>>(fea, out);
}